// Round 1
// baseline (4006.010 us; speedup 1.0000x reference)
//
#include <hip/hip_runtime.h>

#define N_PTS 8192
#define KNN_K 24

__constant__ float c_omega[10] = {
  1.0f, 0.3981071705534972f, 0.15848931924611134f, 0.06309573444801933f,
  0.025118864315095794f, 0.01f, 0.003981071705534973f, 0.0015848931924611134f,
  0.0006309573444801933f, 0.00025118864315095795f
};

__device__ __forceinline__ unsigned keyOf(float f) {
  unsigned u = __float_as_uint(f);
  return (u & 0x80000000u) ? ~u : (u | 0x80000000u);
}

// ---------------- fc1: x = features @ fc1_w + fc1_b ----------------
__global__ __launch_bounds__(256) void fc1_kernel(
    const float* __restrict__ feat, const float* __restrict__ w,
    const float* __restrict__ bias, float* __restrict__ x) {
  int gid = blockIdx.x * 256 + threadIdx.x;   // B*N*128 total
  int row = gid >> 7, c = gid & 127;
  const float* f = feat + (size_t)row * 32;
  float acc = bias[c];
  #pragma unroll
  for (int j = 0; j < 32; ++j) acc = fmaf(f[j], w[j * 128 + c], acc);
  x[gid] = acc;
}

// ---------------- KNN: exact top-24 by (fp32 dist, idx) via 4-pass radix ----------------
// Histogram via wave-aggregated ballots (one atomic per distinct bin per wave-round):
// cheap when bins are concentrated (MSB pass) AND when few lanes active (later passes).
__global__ __launch_bounds__(256) void knn_kernel(
    const float* __restrict__ xyz, int* __restrict__ knn) {
  __shared__ unsigned s_k[N_PTS];       // monotone keys of fp32 distances
  __shared__ unsigned s_hist[256];
  __shared__ unsigned s_wsum[4];
  __shared__ int s_surv[64];
  __shared__ unsigned s_pref, s_rem, s_cnt;

  const int q = blockIdx.x;
  const int b = q >> 13, n = q & (N_PTS - 1);
  const int t = threadIdx.x;
  const int lane = t & 63, wid = t >> 6;
  const float* xb = xyz + (size_t)b * N_PTS * 3;

  float qx = xb[n*3+0], qy = xb[n*3+1], qz = xb[n*3+2];
  // strict fp32 round-to-nearest, no fma — matches numpy association
  float sqq = __fadd_rn(__fadd_rn(__fmul_rn(qx,qx), __fmul_rn(qy,qy)), __fmul_rn(qz,qz));

  if (t == 0) { s_pref = 0u; s_rem = (unsigned)KNN_K; s_cnt = 0u; }

  for (int j = 0; j < 32; ++j) {
    int m = t + 256 * j;
    float cx = xb[m*3+0], cy = xb[m*3+1], cz = xb[m*3+2];
    float sqc = __fadd_rn(__fadd_rn(__fmul_rn(cx,cx), __fmul_rn(cy,cy)), __fmul_rn(cz,cz));
    float dt  = __fadd_rn(__fadd_rn(__fmul_rn(qx,cx), __fmul_rn(qy,cy)), __fmul_rn(qz,cz));
    float d = __fsub_rn(__fadd_rn(sqq, sqc), __fmul_rn(2.0f, dt));
    s_k[m] = keyOf(d);
  }
  __syncthreads();

  // 4 radix passes, MSB->LSB: find exact key of 24th smallest (with duplicates)
  for (int p = 3; p >= 0; --p) {
    unsigned pref = s_pref;
    unsigned rem = s_rem;
    __syncthreads();
    s_hist[t] = 0u;
    __syncthreads();
    const int shift = 8 * p;
    for (int j = 0; j < 32; ++j) {
      int m = t + 256 * j;
      unsigned k = s_k[m];
      bool match = (p == 3) || ((k >> (8 * (p + 1))) == (pref >> (8 * (p + 1))));
      unsigned bin = (k >> shift) & 255u;
      unsigned long long alive = __ballot(match);
      while (alive) {
        int leader = __ffsll(alive) - 1;
        unsigned lb = __shfl(bin, leader, 64);
        unsigned long long grp = __ballot(match && (bin == lb));
        if (lane == leader) atomicAdd(&s_hist[lb], (unsigned)__popcll(grp));
        alive &= ~grp;
      }
    }
    __syncthreads();
    // 256-entry prefix sum: shfl scan within wave + cross-wave offsets
    unsigned v = s_hist[t];
    unsigned sum = v;
    #pragma unroll
    for (int off = 1; off < 64; off <<= 1) {
      unsigned up = __shfl_up(sum, off, 64);
      if (lane >= off) sum += up;
    }
    if (lane == 63) s_wsum[wid] = sum;
    __syncthreads();
    unsigned add = 0u;
    #pragma unroll
    for (int w2 = 0; w2 < 3; ++w2) if (w2 < wid) add += s_wsum[w2];
    unsigned cum = sum + add;
    unsigned prev = cum - v;
    if (cum >= rem && prev < rem) {
      s_pref = pref | (((unsigned)t) << shift);
      s_rem = rem - prev;
    }
    __syncthreads();
  }
  unsigned k24 = s_pref;   // exact key of the 24th smallest distance

  // capture all elements with key <= k24 (<=23 strictly below + ties; cap 64)
  for (int j = 0; j < 32; ++j) {
    int m = t + 256 * j;
    if (s_k[m] <= k24) {
      unsigned p = atomicAdd(&s_cnt, 1u);
      if (p < 64u) s_surv[p] = m;
    }
  }
  __syncthreads();

  if (t < 64) {
    unsigned cnt = s_cnt;
    int S = (int)((cnt < 64u) ? cnt : 64u);
    unsigned long long key = ~0ULL;
    if (t < S) {
      int m = s_surv[t];
      key = (((unsigned long long)s_k[m]) << 32) | (unsigned)m;
    }
    // 64-lane bitonic sort ascending by (dist-key, idx) — np's stable top_k order
    for (int size = 2; size <= 64; size <<= 1) {
      for (int stride = size >> 1; stride > 0; stride >>= 1) {
        unsigned long long pk = __shfl_xor(key, stride, 64);
        bool lower = (t & stride) == 0;
        bool up = (t & size) == 0;
        bool pLess = pk < key;
        bool take = (lower == up) ? pLess : !pLess;
        key = take ? pk : key;
      }
    }
    if (t < KNN_K) knn[(size_t)q * KNN_K + t] = (int)(key & 0xFFFFFFFFu);
  }
}

// ---------------- fused per-query edge pipeline (k-split, weights in registers) ----
// Each of 4 waves owns a 32-row K-slice of W in VGPRs (lane holds 2 columns).
// k-loop: wave-uniform broadcast ds_read_b128 of activations, no barriers inside.
// Cross-wave K-reduction through a 24 KB LDS partial buffer in two e-halves.

#define ZACC { _Pragma("unroll") for (int zz = 0; zz < 24; ++zz) { acc[zz][0] = 0.f; acc[zz][1] = 0.f; } }

template<int KMAX>
__device__ __forceinline__ void wload(const float* __restrict__ W, int k0, int kn,
                                      int c0, float2 (&w)[32]) {
  #pragma unroll
  for (int i = 0; i < KMAX; ++i)
    if (i < kn) w[i] = *(const float2*)&W[(k0 + i) * 128 + c0];
}

template<int KITERS>
__device__ __forceinline__ void kloop(const float* __restrict__ inL, int ldin,
                                      const float2 (&w)[32], int k0, int kn,
                                      float (&acc)[24][2]) {
  #pragma unroll
  for (int g = 0; g < KITERS; ++g) {
    const int kk = g * 4;
    if (kk < kn) {
      #pragma unroll
      for (int e = 0; e < 24; ++e) {
        const float4 p = *(const float4*)&inL[e * ldin + k0 + kk];
        acc[e][0] = fmaf(p.x, w[kk+0].x, acc[e][0]);
        acc[e][1] = fmaf(p.x, w[kk+0].y, acc[e][1]);
        acc[e][0] = fmaf(p.y, w[kk+1].x, acc[e][0]);
        acc[e][1] = fmaf(p.y, w[kk+1].y, acc[e][1]);
        acc[e][0] = fmaf(p.z, w[kk+2].x, acc[e][0]);
        acc[e][1] = fmaf(p.z, w[kk+2].y, acc[e][1]);
        acc[e][0] = fmaf(p.w, w[kk+3].x, acc[e][0]);
        acc[e][1] = fmaf(p.w, w[kk+3].y, acc[e][1]);
      }
    }
  }
}

// sum 4 wave-partials + bias (+relu) -> out[24*128]; sP is 4*12*128 floats
__device__ __forceinline__ void kreduce(float (&acc)[24][2], const float* __restrict__ bias,
                                        float* __restrict__ out, float* sP,
                                        int t, int wid, int c0, bool relu) {
  #pragma unroll
  for (int h = 0; h < 2; ++h) {
    __syncthreads();    // all k-loops done / previous sP consumers done
    #pragma unroll
    for (int r = 0; r < 12; ++r)
      *(float2*)&sP[(wid * 12 + r) * 128 + c0] =
          make_float2(acc[h * 12 + r][0], acc[h * 12 + r][1]);
    __syncthreads();
    #pragma unroll
    for (int ii = 0; ii < 6; ++ii) {
      int i = t + ii * 256;
      float s = sP[i] + sP[i + 1536] + sP[i + 3072] + sP[i + 4608] + bias[i & 127];
      out[h * 1536 + i] = relu ? fmaxf(s, 0.f) : s;
    }
  }
  __syncthreads();      // out ready for consumers
}

__global__ __launch_bounds__(256, 2) void edge_kernel(
    const float* __restrict__ xyz, const float* __restrict__ x,
    const int* __restrict__ knn,
    const float* __restrict__ d1w, const float* __restrict__ d1b,
    const float* __restrict__ d2w, const float* __restrict__ d2b,
    const float* __restrict__ g1w, const float* __restrict__ g1b,
    const float* __restrict__ g2w, const float* __restrict__ g2b,
    const float* __restrict__ fc2w, const float* __restrict__ fc2b,
    float* __restrict__ out_res, float* __restrict__ out_attn) {
  __shared__ __align__(16) float sA[3072];   // v -> v+pos_enc
  __shared__ __align__(16) float sB[3072];   // h1 -> u -> logits
  __shared__ __align__(16) float sC[3072];   // pos_enc -> h2
  __shared__ __align__(16) float sP[6144];   // pe (first 1536) then K-partials (24 KB)
  __shared__ __align__(16) float sXQ[128];
  __shared__ __align__(16) float sR[128];
  __shared__ float sG[96];
  __shared__ int sIdx[KNN_K];

  const int q = blockIdx.x;
  const int b = q >> 13, n = q & (N_PTS - 1);
  const int t = threadIdx.x;
  const int lane = t & 63, wid = t >> 6;
  const int c0 = lane * 2;                   // this lane's 2 output columns
  const float* xb = xyz + (size_t)b * N_PTS * 3;
  const float* xfb = x + (size_t)b * N_PTS * 128;

  float2 wreg[32];
  const int k0s = wid * 16, kns = (wid == 3) ? 12 : 16;  // stage-1 K=60 split 16/16/16/12
  const int k0 = wid * 32;                               // K=128 split
  wload<16>(d1w, k0s, kns, c0, wreg);        // issue stage-1 weight loads ASAP

  if (t < KNN_K) sIdx[t] = knn[(size_t)q * KNN_K + t] & (N_PTS - 1);  // clamp: finite on any bug
  if (t >= 128) sXQ[t - 128] = xfb[(size_t)n * 128 + (t - 128)];
  __syncthreads();
  if (t < 72) {
    int e = t / 3, c = t - e * 3;
    sG[e * 4 + c] = xb[n * 3 + c] - xb[sIdx[e] * 3 + c];
  }
  #pragma unroll
  for (int ii = 0; ii < 12; ++ii) {          // gather v (needed only after stage 2)
    int i = t + ii * 256;
    sA[i] = xfb[(size_t)sIdx[i >> 7] * 128 + (i & 127)];
  }
  __syncthreads();
  // positional encoding into sP[e*64 + r], r = c*20 + (cos?10:0) + j
  for (int i = t; i < 24 * 60; i += 256) {
    int e = i / 60, r = i - e * 60;
    int c = r / 20, inner = r - c * 20;
    int jj = (inner >= 10) ? inner - 10 : inner;
    float v = sG[e * 4 + c] * c_omega[jj];
    sP[e * 64 + r] = (inner >= 10) ? __cosf(v) : __sinf(v);
  }
  __syncthreads();

  float acc[24][2];

  // stage 1: h1 = relu(pe @ d1w + d1b)
  ZACC;
  kloop<4>(sP, 64, wreg, k0s, kns, acc);
  wload<32>(d2w, k0, 32, c0, wreg);          // prefetch next weights under reduction
  kreduce(acc, d1b, sB, sP, t, wid, c0, true);

  // stage 2: pos_enc = h1 @ d2w + d2b
  ZACC;
  kloop<8>(sB, 128, wreg, k0, 32, acc);
  wload<32>(g1w, k0, 32, c0, wreg);
  kreduce(acc, d2b, sC, sP, t, wid, c0, false);

  // u = xq - v + pos_enc -> sB ; sA = v + pos_enc
  #pragma unroll
  for (int ii = 0; ii < 12; ++ii) {
    int i = t + ii * 256;
    float v = sA[i], pe = sC[i];
    sB[i] = sXQ[i & 127] - v + pe;
    sA[i] = v + pe;
  }
  __syncthreads();

  // stage 3: h2 = relu(u @ g1w + g1b)
  ZACC;
  kloop<8>(sB, 128, wreg, k0, 32, acc);
  wload<32>(g2w, k0, 32, c0, wreg);
  kreduce(acc, g1b, sC, sP, t, wid, c0, true);

  // stage 4: logits = h2 @ g2w + g2b
  ZACC;
  kloop<8>(sC, 128, wreg, k0, 32, acc);
  wload<32>(fc2w, k0, 32, c0, wreg);
  kreduce(acc, g2b, sB, sP, t, wid, c0, false);

  // softmax over K per column + res accumulation
  if (t < 128) {
    const float scale = 0.08838834764831845f;  // 1/sqrt(128)
    float mx = -3.0e38f;
    #pragma unroll
    for (int e = 0; e < KNN_K; ++e) mx = fmaxf(mx, sB[e * 128 + t] * scale);
    float s = 0.f;
    #pragma unroll
    for (int e = 0; e < KNN_K; ++e) {
      float ex = __expf(sB[e * 128 + t] * scale - mx);
      sB[e * 128 + t] = ex;
      s += ex;
    }
    float inv = 1.0f / s;
    float r = 0.f;
    size_t base = (size_t)q * KNN_K * 128 + t;
    #pragma unroll
    for (int e = 0; e < KNN_K; ++e) {
      float p = sB[e * 128 + t] * inv;
      out_attn[base + (size_t)e * 128] = p;
      r = fmaf(p, sA[e * 128 + t], r);
    }
    sR[t] = r;
  }
  __syncthreads();

  // final: out_res = sR @ fc2w + fc2b + xq   (k-split, fc2w already in wreg)
  float a0 = 0.f, a1 = 0.f;
  #pragma unroll
  for (int g = 0; g < 8; ++g) {
    const float4 p = *(const float4*)&sR[k0 + g * 4];
    a0 = fmaf(p.x, wreg[g*4+0].x, a0); a1 = fmaf(p.x, wreg[g*4+0].y, a1);
    a0 = fmaf(p.y, wreg[g*4+1].x, a0); a1 = fmaf(p.y, wreg[g*4+1].y, a1);
    a0 = fmaf(p.z, wreg[g*4+2].x, a0); a1 = fmaf(p.z, wreg[g*4+2].y, a1);
    a0 = fmaf(p.w, wreg[g*4+3].x, a0); a1 = fmaf(p.w, wreg[g*4+3].y, a1);
  }
  *(float2*)&sP[wid * 128 + c0] = make_float2(a0, a1);
  __syncthreads();
  if (t < 128)
    out_res[(size_t)q * 128 + t] =
        sP[t] + sP[128 + t] + sP[256 + t] + sP[384 + t] + fc2b[t] + sXQ[t];
}

extern "C" void kernel_launch(void* const* d_in, const int* in_sizes, int n_in,
                              void* d_out, int out_size, void* d_ws, size_t ws_size,
                              hipStream_t stream) {
  const float* feat = (const float*)d_in[0];
  const float* xyz  = (const float*)d_in[1];
  const float* fc1w = (const float*)d_in[2];
  const float* fc1b = (const float*)d_in[3];
  const float* fc2w = (const float*)d_in[4];
  const float* fc2b = (const float*)d_in[5];
  const float* d1w  = (const float*)d_in[6];
  const float* d1b  = (const float*)d_in[7];
  const float* d2w  = (const float*)d_in[8];
  const float* d2b  = (const float*)d_in[9];
  const float* g1w  = (const float*)d_in[10];
  const float* g1b  = (const float*)d_in[11];
  const float* g2w  = (const float*)d_in[12];
  const float* g2b  = (const float*)d_in[13];

  float* x = (float*)d_ws;                                        // 2*8192*128 fp32 = 8 MB
  int* knn = (int*)((char*)d_ws + (size_t)2 * 8192 * 128 * 4);    // 2*8192*24 int32

  float* out_res  = (float*)d_out;                                // [2,8192,128] fp32
  float* out_attn = out_res + (size_t)2 * 8192 * 128;             // [2,8192,24,128] fp32

  fc1_kernel<<<dim3((2 * 8192 * 128) / 256), 256, 0, stream>>>(feat, fc1w, fc1b, x);
  knn_kernel<<<dim3(2 * 8192), 256, 0, stream>>>(xyz, knn);
  edge_kernel<<<dim3(2 * 8192), 256, 0, stream>>>(xyz, x, knn,
                                                  d1w, d1b, d2w, d2b,
                                                  g1w, g1b, g2w, g2b,
                                                  fc2w, fc2b, out_res, out_attn);
}

// Round 2
// 2453.632 us; speedup vs baseline: 1.6327x; 1.6327x over previous
//
#include <hip/hip_runtime.h>

#define N_PTS 8192
#define KNN_K 24

__constant__ float c_omega[10] = {
  1.0f, 0.3981071705534972f, 0.15848931924611134f, 0.06309573444801933f,
  0.025118864315095794f, 0.01f, 0.003981071705534973f, 0.0015848931924611134f,
  0.0006309573444801933f, 0.00025118864315095795f
};

__device__ __forceinline__ unsigned keyOf(float f) {
  unsigned u = __float_as_uint(f);
  return (u & 0x80000000u) ? ~u : (u | 0x80000000u);
}

// ---------------- fc1: x = features @ fc1_w + fc1_b ----------------
__global__ __launch_bounds__(256) void fc1_kernel(
    const float* __restrict__ feat, const float* __restrict__ w,
    const float* __restrict__ bias, float* __restrict__ x) {
  int gid = blockIdx.x * 256 + threadIdx.x;   // B*N*128 total
  int row = gid >> 7, c = gid & 127;
  const float* f = feat + (size_t)row * 32;
  float acc = bias[c];
  #pragma unroll
  for (int j = 0; j < 32; ++j) acc = fmaf(f[j], w[j * 128 + c], acc);
  x[gid] = acc;
}

// ---------------- KNN: exact top-24 by (fp32 dist, idx), keys in registers ------
// Each thread owns 32 candidate keys in VGPRs; 4-pass radix select reads regs
// (no 32KB LDS key array, no re-scans). Histogram via wave-aggregated ballots.
__global__ __launch_bounds__(256) void knn_kernel(
    const float* __restrict__ xyz, int* __restrict__ knn) {
  __shared__ unsigned s_hist[256];
  __shared__ unsigned s_wsum[4];
  __shared__ unsigned long long s_surv[64];
  __shared__ unsigned s_pref, s_rem, s_cnt;

  const int q = blockIdx.x;
  const int b = q >> 13, n = q & (N_PTS - 1);
  const int t = threadIdx.x;
  const int lane = t & 63, wid = t >> 6;
  const float* xb = xyz + (size_t)b * N_PTS * 3;

  float qx = xb[n*3+0], qy = xb[n*3+1], qz = xb[n*3+2];
  // strict fp32 round-to-nearest, no fma — matches numpy association
  float sqq = __fadd_rn(__fadd_rn(__fmul_rn(qx,qx), __fmul_rn(qy,qy)), __fmul_rn(qz,qz));

  if (t == 0) { s_pref = 0u; s_rem = (unsigned)KNN_K; s_cnt = 0u; }

  unsigned key[32];
  #pragma unroll
  for (int j = 0; j < 32; ++j) {
    int m = t + 256 * j;
    float cx = xb[m*3+0], cy = xb[m*3+1], cz = xb[m*3+2];
    float sqc = __fadd_rn(__fadd_rn(__fmul_rn(cx,cx), __fmul_rn(cy,cy)), __fmul_rn(cz,cz));
    float dt  = __fadd_rn(__fadd_rn(__fmul_rn(qx,cx), __fmul_rn(qy,cy)), __fmul_rn(qz,cz));
    float d = __fsub_rn(__fadd_rn(sqq, sqc), __fmul_rn(2.0f, dt));
    key[j] = keyOf(d);
  }
  __syncthreads();   // covers s_pref/s_rem/s_cnt init

  // 4 radix passes, MSB->LSB: find exact key of 24th smallest (with duplicates)
  for (int p = 3; p >= 0; --p) {
    unsigned pref = s_pref;
    unsigned rem = s_rem;
    __syncthreads();
    s_hist[t] = 0u;
    __syncthreads();
    const int shift = 8 * p;
    for (int j = 0; j < 32; ++j) {
      unsigned k = key[j];
      bool match = (p == 3) || ((k >> (8 * (p + 1))) == (pref >> (8 * (p + 1))));
      unsigned bin = (k >> shift) & 255u;
      unsigned long long alive = __ballot(match);
      while (alive) {
        int leader = __ffsll(alive) - 1;
        unsigned lb = __shfl(bin, leader, 64);
        unsigned long long grp = __ballot(match && (bin == lb));
        if (lane == leader) atomicAdd(&s_hist[lb], (unsigned)__popcll(grp));
        alive &= ~grp;
      }
    }
    __syncthreads();
    // 256-entry prefix sum: shfl scan within wave + cross-wave offsets
    unsigned v = s_hist[t];
    unsigned sum = v;
    #pragma unroll
    for (int off = 1; off < 64; off <<= 1) {
      unsigned up = __shfl_up(sum, off, 64);
      if (lane >= off) sum += up;
    }
    if (lane == 63) s_wsum[wid] = sum;
    __syncthreads();
    unsigned add = 0u;
    #pragma unroll
    for (int w2 = 0; w2 < 3; ++w2) if (w2 < wid) add += s_wsum[w2];
    unsigned cum = sum + add;
    unsigned prev = cum - v;
    if (cum >= rem && prev < rem) {
      s_pref = pref | (((unsigned)t) << shift);
      s_rem = rem - prev;
    }
    __syncthreads();
  }
  unsigned k24 = s_pref;   // exact key of the 24th smallest distance

  // capture all elements with key <= k24 (<=23 strictly below + ties; cap 64)
  #pragma unroll
  for (int j = 0; j < 32; ++j) {
    if (key[j] <= k24) {
      unsigned pp = atomicAdd(&s_cnt, 1u);
      if (pp < 64u)
        s_surv[pp] = (((unsigned long long)key[j]) << 32) | (unsigned)(t + 256 * j);
    }
  }
  __syncthreads();

  if (t < 64) {
    unsigned cnt = s_cnt;
    int S = (int)((cnt < 64u) ? cnt : 64u);
    unsigned long long kv = ~0ULL;
    if (t < S) kv = s_surv[t];
    // 64-lane bitonic sort ascending by (dist-key, idx) — np's stable top_k order
    for (int size = 2; size <= 64; size <<= 1) {
      for (int stride = size >> 1; stride > 0; stride >>= 1) {
        unsigned long long pk = __shfl_xor(kv, stride, 64);
        bool lower = (t & stride) == 0;
        bool up = (t & size) == 0;
        bool pLess = pk < kv;
        bool take = (lower == up) ? pLess : !pLess;
        kv = take ? pk : kv;
      }
    }
    if (t < KNN_K) knn[(size_t)q * KNN_K + t] = (int)(kv & 0xFFFFFFFFu);
  }
}

// ---------------- fused per-query edge pipeline (k-split, chunked reg weights) ----
// Each of 4 waves owns a 32-row K-slice of each W; lane holds 2 output columns.
// Weights stream through two 8-row register chunks (wA/wB, 16 VGPR each) so peak
// live regs ~100 (acc 48 + w 32 + temps) — fits 128 VGPRs, NO scratch spill.
// k-loops read activations via wave-uniform broadcast ds_read_b128, zero barriers.

#define ZACC { _Pragma("unroll") for (int zz = 0; zz < 24; ++zz) { acc[zz][0] = 0.f; acc[zz][1] = 0.f; } }

__device__ __forceinline__ void wload8(const float* __restrict__ W, int kbase, int kn,
                                       int c0, float2 (&w)[8]) {
  #pragma unroll
  for (int i = 0; i < 8; ++i)
    if (i < kn) w[i] = *(const float2*)&W[(kbase + i) * 128 + c0];
}

__device__ __forceinline__ void kloop8(const float* __restrict__ inL, int ldin,
                                       const float2 (&w)[8], int kbase, int kn,
                                       float (&acc)[24][2]) {
  #pragma unroll
  for (int g = 0; g < 2; ++g) {
    const int kk = g * 4;
    if (kk < kn) {
      #pragma unroll
      for (int e = 0; e < 24; ++e) {
        const float4 p = *(const float4*)&inL[e * ldin + kbase + kk];
        acc[e][0] = fmaf(p.x, w[kk+0].x, acc[e][0]);
        acc[e][1] = fmaf(p.x, w[kk+0].y, acc[e][1]);
        acc[e][0] = fmaf(p.y, w[kk+1].x, acc[e][0]);
        acc[e][1] = fmaf(p.y, w[kk+1].y, acc[e][1]);
        acc[e][0] = fmaf(p.z, w[kk+2].x, acc[e][0]);
        acc[e][1] = fmaf(p.z, w[kk+2].y, acc[e][1]);
        acc[e][0] = fmaf(p.w, w[kk+3].x, acc[e][0]);
        acc[e][1] = fmaf(p.w, w[kk+3].y, acc[e][1]);
      }
    }
  }
}

// sum 4 wave-partials + bias (+relu) -> out[24*128]; sP is 4*12*128 floats
__device__ __forceinline__ void kreduce(float (&acc)[24][2], const float* __restrict__ bias,
                                        float* __restrict__ out, float* sP,
                                        int t, int wid, int c0, bool relu) {
  #pragma unroll
  for (int h = 0; h < 2; ++h) {
    __syncthreads();    // all k-loops done / previous sP consumers done
    #pragma unroll
    for (int r = 0; r < 12; ++r)
      *(float2*)&sP[(wid * 12 + r) * 128 + c0] =
          make_float2(acc[h * 12 + r][0], acc[h * 12 + r][1]);
    __syncthreads();
    #pragma unroll
    for (int ii = 0; ii < 6; ++ii) {
      int i = t + ii * 256;
      float s = sP[i] + sP[i + 1536] + sP[i + 3072] + sP[i + 4608] + bias[i & 127];
      out[h * 1536 + i] = relu ? fmaxf(s, 0.f) : s;
    }
  }
  __syncthreads();      // out ready for consumers
}

__global__ __launch_bounds__(256, 2) void edge_kernel(
    const float* __restrict__ xyz, const float* __restrict__ x,
    const int* __restrict__ knn,
    const float* __restrict__ d1w, const float* __restrict__ d1b,
    const float* __restrict__ d2w, const float* __restrict__ d2b,
    const float* __restrict__ g1w, const float* __restrict__ g1b,
    const float* __restrict__ g2w, const float* __restrict__ g2b,
    const float* __restrict__ fc2w, const float* __restrict__ fc2b,
    float* __restrict__ out_res, float* __restrict__ out_attn) {
  __shared__ __align__(16) float sA[3072];   // v -> v+pos_enc
  __shared__ __align__(16) float sB[3072];   // h1 -> u -> logits
  __shared__ __align__(16) float sC[3072];   // pos_enc -> h2
  __shared__ __align__(16) float sP[6144];   // pe (first 1536) then K-partials (24 KB)
  __shared__ __align__(16) float sXQ[128];
  __shared__ __align__(16) float sR[128];
  __shared__ float sG[96];
  __shared__ int sIdx[KNN_K];

  const int q = blockIdx.x;
  const int b = q >> 13, n = q & (N_PTS - 1);
  const int t = threadIdx.x;
  const int lane = t & 63, wid = t >> 6;
  const int c0 = lane * 2;                   // this lane's 2 output columns
  const int k0 = wid * 32;                   // this wave's 32-row K-slice
  const float* xb = xyz + (size_t)b * N_PTS * 3;
  const float* xfb = x + (size_t)b * N_PTS * 128;

  float2 wA[8], wB[8];
  float acc[24][2];

  // stage-1 (K=60) split 16/16/16/12 across waves; prefetch both chunks now
  const int k0s = wid * 16, kns = (wid == 3) ? 12 : 16;
  wload8(d1w, k0s, 8, c0, wA);
  wload8(d1w, k0s + 8, kns - 8, c0, wB);

  if (t < KNN_K) sIdx[t] = knn[(size_t)q * KNN_K + t] & (N_PTS - 1);  // clamp: finite on any bug
  if (t >= 128) sXQ[t - 128] = xfb[(size_t)n * 128 + (t - 128)];
  __syncthreads();
  if (t < 72) {
    int e = t / 3, c = t - e * 3;
    sG[e * 4 + c] = xb[n * 3 + c] - xb[sIdx[e] * 3 + c];
  }
  #pragma unroll
  for (int ii = 0; ii < 3; ++ii) {           // gather v: 768 float4 loads
    int i4 = t + ii * 256;
    int e = i4 >> 5, c4 = (i4 & 31) * 4;
    *(float4*)&sA[e * 128 + c4] = *(const float4*)&xfb[(size_t)sIdx[e] * 128 + c4];
  }
  __syncthreads();
  // positional encoding into sP[e*64 + r], r = c*20 + (cos?10:0) + j
  for (int i = t; i < 24 * 60; i += 256) {
    int e = i / 60, r = i - e * 60;
    int c = r / 20, inner = r - c * 20;
    int jj = (inner >= 10) ? inner - 10 : inner;
    float v = sG[e * 4 + c] * c_omega[jj];
    sP[e * 64 + r] = (inner >= 10) ? __cosf(v) : __sinf(v);
  }
  __syncthreads();

  // stage 1: h1 = relu(pe @ d1w + d1b)
  ZACC;
  kloop8(sP, 64, wA, k0s, 8, acc);        wload8(d2w, k0, 8, c0, wA);
  kloop8(sP, 64, wB, k0s + 8, kns - 8, acc);  wload8(d2w, k0 + 8, 8, c0, wB);
  kreduce(acc, d1b, sB, sP, t, wid, c0, true);

  // stage 2: pos_enc = h1 @ d2w + d2b
  ZACC;
  kloop8(sB, 128, wA, k0, 8, acc);        wload8(d2w, k0 + 16, 8, c0, wA);
  kloop8(sB, 128, wB, k0 + 8, 8, acc);    wload8(d2w, k0 + 24, 8, c0, wB);
  kloop8(sB, 128, wA, k0 + 16, 8, acc);   wload8(g1w, k0, 8, c0, wA);
  kloop8(sB, 128, wB, k0 + 24, 8, acc);   wload8(g1w, k0 + 8, 8, c0, wB);
  kreduce(acc, d2b, sC, sP, t, wid, c0, false);

  // u = xq - v + pos_enc -> sB ; sA = v + pos_enc
  #pragma unroll
  for (int ii = 0; ii < 12; ++ii) {
    int i = t + ii * 256;
    float v = sA[i], pe = sC[i];
    sB[i] = sXQ[i & 127] - v + pe;
    sA[i] = v + pe;
  }
  __syncthreads();

  // stage 3: h2 = relu(u @ g1w + g1b)
  ZACC;
  kloop8(sB, 128, wA, k0, 8, acc);        wload8(g1w, k0 + 16, 8, c0, wA);
  kloop8(sB, 128, wB, k0 + 8, 8, acc);    wload8(g1w, k0 + 24, 8, c0, wB);
  kloop8(sB, 128, wA, k0 + 16, 8, acc);   wload8(g2w, k0, 8, c0, wA);
  kloop8(sB, 128, wB, k0 + 24, 8, acc);   wload8(g2w, k0 + 8, 8, c0, wB);
  kreduce(acc, g1b, sC, sP, t, wid, c0, true);

  // stage 4: logits = h2 @ g2w + g2b
  ZACC;
  kloop8(sC, 128, wA, k0, 8, acc);        wload8(g2w, k0 + 16, 8, c0, wA);
  kloop8(sC, 128, wB, k0 + 8, 8, acc);    wload8(g2w, k0 + 24, 8, c0, wB);
  kloop8(sC, 128, wA, k0 + 16, 8, acc);   wload8(fc2w, k0, 8, c0, wA);
  kloop8(sC, 128, wB, k0 + 24, 8, acc);   wload8(fc2w, k0 + 8, 8, c0, wB);
  kreduce(acc, g2b, sB, sP, t, wid, c0, false);

  // softmax over K per column + res accumulation
  if (t < 128) {
    const float scale = 0.08838834764831845f;  // 1/sqrt(128)
    float mx = -3.0e38f;
    #pragma unroll
    for (int e = 0; e < KNN_K; ++e) mx = fmaxf(mx, sB[e * 128 + t] * scale);
    float s = 0.f;
    #pragma unroll
    for (int e = 0; e < KNN_K; ++e) {
      float ex = __expf(sB[e * 128 + t] * scale - mx);
      sB[e * 128 + t] = ex;
      s += ex;
    }
    float inv = 1.0f / s;
    float r = 0.f;
    size_t base = (size_t)q * KNN_K * 128 + t;
    #pragma unroll
    for (int e = 0; e < KNN_K; ++e) {
      float p = sB[e * 128 + t] * inv;
      out_attn[base + (size_t)e * 128] = p;
      r = fmaf(p, sA[e * 128 + t], r);
    }
    sR[t] = r;
  }
  __syncthreads();

  // final: out_res = sR @ fc2w + fc2b + xq  (k-split; wA/wB hold fc2w k0..k0+15)
  float a0 = 0.f, a1 = 0.f;
  #pragma unroll
  for (int g = 0; g < 2; ++g) {
    const float4 p = *(const float4*)&sR[k0 + g * 4];
    a0 = fmaf(p.x, wA[g*4+0].x, a0); a1 = fmaf(p.x, wA[g*4+0].y, a1);
    a0 = fmaf(p.y, wA[g*4+1].x, a0); a1 = fmaf(p.y, wA[g*4+1].y, a1);
    a0 = fmaf(p.z, wA[g*4+2].x, a0); a1 = fmaf(p.z, wA[g*4+2].y, a1);
    a0 = fmaf(p.w, wA[g*4+3].x, a0); a1 = fmaf(p.w, wA[g*4+3].y, a1);
  }
  #pragma unroll
  for (int g = 0; g < 2; ++g) {
    const float4 p = *(const float4*)&sR[k0 + 8 + g * 4];
    a0 = fmaf(p.x, wB[g*4+0].x, a0); a1 = fmaf(p.x, wB[g*4+0].y, a1);
    a0 = fmaf(p.y, wB[g*4+1].x, a0); a1 = fmaf(p.y, wB[g*4+1].y, a1);
    a0 = fmaf(p.z, wB[g*4+2].x, a0); a1 = fmaf(p.z, wB[g*4+2].y, a1);
    a0 = fmaf(p.w, wB[g*4+3].x, a0); a1 = fmaf(p.w, wB[g*4+3].y, a1);
  }
  wload8(fc2w, k0 + 16, 8, c0, wA);
  wload8(fc2w, k0 + 24, 8, c0, wB);
  #pragma unroll
  for (int g = 0; g < 2; ++g) {
    const float4 p = *(const float4*)&sR[k0 + 16 + g * 4];
    a0 = fmaf(p.x, wA[g*4+0].x, a0); a1 = fmaf(p.x, wA[g*4+0].y, a1);
    a0 = fmaf(p.y, wA[g*4+1].x, a0); a1 = fmaf(p.y, wA[g*4+1].y, a1);
    a0 = fmaf(p.z, wA[g*4+2].x, a0); a1 = fmaf(p.z, wA[g*4+2].y, a1);
    a0 = fmaf(p.w, wA[g*4+3].x, a0); a1 = fmaf(p.w, wA[g*4+3].y, a1);
  }
  #pragma unroll
  for (int g = 0; g < 2; ++g) {
    const float4 p = *(const float4*)&sR[k0 + 24 + g * 4];
    a0 = fmaf(p.x, wB[g*4+0].x, a0); a1 = fmaf(p.x, wB[g*4+0].y, a1);
    a0 = fmaf(p.y, wB[g*4+1].x, a0); a1 = fmaf(p.y, wB[g*4+1].y, a1);
    a0 = fmaf(p.z, wB[g*4+2].x, a0); a1 = fmaf(p.z, wB[g*4+2].y, a1);
    a0 = fmaf(p.w, wB[g*4+3].x, a0); a1 = fmaf(p.w, wB[g*4+3].y, a1);
  }
  *(float2*)&sP[wid * 128 + c0] = make_float2(a0, a1);
  __syncthreads();
  if (t < 128)
    out_res[(size_t)q * 128 + t] =
        sP[t] + sP[128 + t] + sP[256 + t] + sP[384 + t] + fc2b[t] + sXQ[t];
}

extern "C" void kernel_launch(void* const* d_in, const int* in_sizes, int n_in,
                              void* d_out, int out_size, void* d_ws, size_t ws_size,
                              hipStream_t stream) {
  const float* feat = (const float*)d_in[0];
  const float* xyz  = (const float*)d_in[1];
  const float* fc1w = (const float*)d_in[2];
  const float* fc1b = (const float*)d_in[3];
  const float* fc2w = (const float*)d_in[4];
  const float* fc2b = (const float*)d_in[5];
  const float* d1w  = (const float*)d_in[6];
  const float* d1b  = (const float*)d_in[7];
  const float* d2w  = (const float*)d_in[8];
  const float* d2b  = (const float*)d_in[9];
  const float* g1w  = (const float*)d_in[10];
  const float* g1b  = (const float*)d_in[11];
  const float* g2w  = (const float*)d_in[12];
  const float* g2b  = (const float*)d_in[13];

  float* x = (float*)d_ws;                                        // 2*8192*128 fp32 = 8 MB
  int* knn = (int*)((char*)d_ws + (size_t)2 * 8192 * 128 * 4);    // 2*8192*24 int32

  float* out_res  = (float*)d_out;                                // [2,8192,128] fp32
  float* out_attn = out_res + (size_t)2 * 8192 * 128;             // [2,8192,24,128] fp32

  fc1_kernel<<<dim3((2 * 8192 * 128) / 256), 256, 0, stream>>>(feat, fc1w, fc1b, x);
  knn_kernel<<<dim3(2 * 8192), 256, 0, stream>>>(xyz, knn);
  edge_kernel<<<dim3(2 * 8192), 256, 0, stream>>>(xyz, x, knn,
                                                  d1w, d1b, d2w, d2b,
                                                  g1w, g1b, g2w, g2b,
                                                  fc2w, fc2b, out_res, out_attn);
}

// Round 3
// 2092.682 us; speedup vs baseline: 1.9143x; 1.1725x over previous
//
#include <hip/hip_runtime.h>

#define N_PTS 8192
#define KNN_K 24

__constant__ float c_omega[10] = {
  1.0f, 0.3981071705534972f, 0.15848931924611134f, 0.06309573444801933f,
  0.025118864315095794f, 0.01f, 0.003981071705534973f, 0.0015848931924611134f,
  0.0006309573444801933f, 0.00025118864315095795f
};

__device__ __forceinline__ unsigned keyOf(float f) {
  unsigned u = __float_as_uint(f);
  return (u & 0x80000000u) ? ~u : (u | 0x80000000u);
}

// ---------------- fc1: x = features @ fc1_w + fc1_b ----------------
__global__ __launch_bounds__(256) void fc1_kernel(
    const float* __restrict__ feat, const float* __restrict__ w,
    const float* __restrict__ bias, float* __restrict__ x) {
  int gid = blockIdx.x * 256 + threadIdx.x;   // B*N*128 total
  int row = gid >> 7, c = gid & 127;
  const float* f = feat + (size_t)row * 32;
  float acc = bias[c];
  #pragma unroll
  for (int j = 0; j < 32; ++j) acc = fmaf(f[j], w[j * 128 + c], acc);
  x[gid] = acc;
}

// ---------------- KNN: exact top-24 by (fp32 dist, idx), keys in registers ------
__global__ __launch_bounds__(256) void knn_kernel(
    const float* __restrict__ xyz, int* __restrict__ knn) {
  __shared__ unsigned s_hist[256];
  __shared__ unsigned s_wsum[4];
  __shared__ unsigned long long s_surv[64];
  __shared__ unsigned s_pref, s_rem, s_cnt;

  const int q = blockIdx.x;
  const int b = q >> 13, n = q & (N_PTS - 1);
  const int t = threadIdx.x;
  const int lane = t & 63, wid = t >> 6;
  const float* xb = xyz + (size_t)b * N_PTS * 3;

  float qx = xb[n*3+0], qy = xb[n*3+1], qz = xb[n*3+2];
  // strict fp32 round-to-nearest, no fma — matches numpy association
  float sqq = __fadd_rn(__fadd_rn(__fmul_rn(qx,qx), __fmul_rn(qy,qy)), __fmul_rn(qz,qz));

  if (t == 0) { s_pref = 0u; s_rem = (unsigned)KNN_K; s_cnt = 0u; }

  unsigned key[32];
  #pragma unroll
  for (int j = 0; j < 32; ++j) {
    int m = t + 256 * j;
    float cx = xb[m*3+0], cy = xb[m*3+1], cz = xb[m*3+2];
    float sqc = __fadd_rn(__fadd_rn(__fmul_rn(cx,cx), __fmul_rn(cy,cy)), __fmul_rn(cz,cz));
    float dt  = __fadd_rn(__fadd_rn(__fmul_rn(qx,cx), __fmul_rn(qy,cy)), __fmul_rn(qz,cz));
    float d = __fsub_rn(__fadd_rn(sqq, sqc), __fmul_rn(2.0f, dt));
    key[j] = keyOf(d);
  }
  __syncthreads();   // covers s_pref/s_rem/s_cnt init

  // 4 radix passes, MSB->LSB: find exact key of 24th smallest (with duplicates)
  for (int p = 3; p >= 0; --p) {
    unsigned pref = s_pref;
    unsigned rem = s_rem;
    __syncthreads();
    s_hist[t] = 0u;
    __syncthreads();
    const int shift = 8 * p;
    for (int j = 0; j < 32; ++j) {
      unsigned k = key[j];
      bool match = (p == 3) || ((k >> (8 * (p + 1))) == (pref >> (8 * (p + 1))));
      unsigned bin = (k >> shift) & 255u;
      unsigned long long alive = __ballot(match);
      while (alive) {
        int leader = __ffsll(alive) - 1;
        unsigned lb = __shfl(bin, leader, 64);
        unsigned long long grp = __ballot(match && (bin == lb));
        if (lane == leader) atomicAdd(&s_hist[lb], (unsigned)__popcll(grp));
        alive &= ~grp;
      }
    }
    __syncthreads();
    unsigned v = s_hist[t];
    unsigned sum = v;
    #pragma unroll
    for (int off = 1; off < 64; off <<= 1) {
      unsigned up = __shfl_up(sum, off, 64);
      if (lane >= off) sum += up;
    }
    if (lane == 63) s_wsum[wid] = sum;
    __syncthreads();
    unsigned add = 0u;
    #pragma unroll
    for (int w2 = 0; w2 < 3; ++w2) if (w2 < wid) add += s_wsum[w2];
    unsigned cum = sum + add;
    unsigned prev = cum - v;
    if (cum >= rem && prev < rem) {
      s_pref = pref | (((unsigned)t) << shift);
      s_rem = rem - prev;
    }
    __syncthreads();
  }
  unsigned k24 = s_pref;

  #pragma unroll
  for (int j = 0; j < 32; ++j) {
    if (key[j] <= k24) {
      unsigned pp = atomicAdd(&s_cnt, 1u);
      if (pp < 64u)
        s_surv[pp] = (((unsigned long long)key[j]) << 32) | (unsigned)(t + 256 * j);
    }
  }
  __syncthreads();

  if (t < 64) {
    unsigned cnt = s_cnt;
    int S = (int)((cnt < 64u) ? cnt : 64u);
    unsigned long long kv = ~0ULL;
    if (t < S) kv = s_surv[t];
    for (int size = 2; size <= 64; size <<= 1) {
      for (int stride = size >> 1; stride > 0; stride >>= 1) {
        unsigned long long pk = __shfl_xor(kv, stride, 64);
        bool lower = (t & stride) == 0;
        bool up = (t & size) == 0;
        bool pLess = pk < kv;
        bool take = (lower == up) ? pLess : !pLess;
        kv = take ? pk : kv;
      }
    }
    if (t < KNN_K) knn[(size_t)q * KNN_K + t] = (int)(kv & 0xFFFFFFFFu);
  }
}

// ---------------- fused per-query edge pipeline ----------------
// Round-0 compute layout (thread owns 3 rows x 4 cols; 88-VGPR class, no spill)
// + double-buffered LDS weights with async reg-staged prefetch (T14):
// per 32-row chunk: {ds_write staged regs -> other buf; issue next chunk's
// global loads; compute current chunk; one barrier}. HBM latency hides under
// the ~800-cycle chunk compute instead of being exposed inside barrier pairs.

// stage regs <- global chunk (cnt4 float4s of 1024/896)
#define LOADC(W, foff, cnt4) { _Pragma("unroll") \
  for (int rr = 0; rr < 4; ++rr) { int i4 = t + rr * 256; \
    if (i4 < (cnt4)) st[rr] = *(const float4*)&(W)[(foff) + i4 * 4]; } }
// stage regs -> sW half
#define WRITEC(bufb, cnt4) { _Pragma("unroll") \
  for (int rr = 0; rr < 4; ++rr) { int i4 = t + rr * 256; \
    if (i4 < (cnt4)) *(float4*)&sW[(bufb) * 4096 + i4 * 4] = st[rr]; } }

#define ZACC { _Pragma("unroll") for (int zr = 0; zr < 3; ++zr) \
  { acc[zr][0] = 0.f; acc[zr][1] = 0.f; acc[zr][2] = 0.f; acc[zr][3] = 0.f; } }

template<int ROWS>
__device__ __forceinline__ void cchunk(const float* __restrict__ inL, int ldin, int kbase,
                                       const float* __restrict__ sWb,
                                       int c0, int e0, float (&acc)[3][4]) {
  #pragma unroll 8
  for (int j = 0; j < ROWS; ++j) {
    float4 w = *(const float4*)&sWb[j * 128 + c0];
    #pragma unroll
    for (int r = 0; r < 3; ++r) {
      float p = inL[(e0 + r) * ldin + kbase + j];
      acc[r][0] = fmaf(p, w.x, acc[r][0]);
      acc[r][1] = fmaf(p, w.y, acc[r][1]);
      acc[r][2] = fmaf(p, w.z, acc[r][2]);
      acc[r][3] = fmaf(p, w.w, acc[r][3]);
    }
  }
}

__device__ __forceinline__ void epi(float (&acc)[3][4], const float* __restrict__ bg,
                                    float* __restrict__ out, int c0, int e0, bool relu) {
  float4 bb = *(const float4*)&bg[c0];
  #pragma unroll
  for (int r = 0; r < 3; ++r) {
    float4 o;
    o.x = acc[r][0] + bb.x; o.y = acc[r][1] + bb.y;
    o.z = acc[r][2] + bb.z; o.w = acc[r][3] + bb.w;
    if (relu) { o.x = fmaxf(o.x, 0.f); o.y = fmaxf(o.y, 0.f);
                o.z = fmaxf(o.z, 0.f); o.w = fmaxf(o.w, 0.f); }
    *(float4*)&out[(e0 + r) * 128 + c0] = o;
  }
}

__global__ __launch_bounds__(256, 2) void edge_kernel(
    const float* __restrict__ xyz, const float* __restrict__ x,
    const int* __restrict__ knn,
    const float* __restrict__ d1w, const float* __restrict__ d1b,
    const float* __restrict__ d2w, const float* __restrict__ d2b,
    const float* __restrict__ g1w, const float* __restrict__ g1b,
    const float* __restrict__ g2w, const float* __restrict__ g2b,
    const float* __restrict__ fc2w, const float* __restrict__ fc2b,
    float* __restrict__ out_res, float* __restrict__ out_attn) {
  __shared__ __align__(16) float sW[8192];     // 32 KB: two 16 KB weight-chunk buffers
  __shared__ __align__(16) float sA[3072];     // v -> v+pos_enc
  __shared__ __align__(16) float sB[3072];     // h1 -> u -> logits/probs
  __shared__ __align__(16) float sC[3072];     // pos_enc -> h2
  __shared__ __align__(16) float sPE[24 * 64]; // pe (60 cols, padded)
  __shared__ __align__(16) float sXQ[128];
  __shared__ __align__(16) float sR[128];
  __shared__ float sG[96];
  __shared__ int sIdx[KNN_K];

  const int q = blockIdx.x;
  const int b = q >> 13, n = q & (N_PTS - 1);
  const int t = threadIdx.x;
  const int cg = t & 31, eg = t >> 5;
  const int c0 = cg * 4, e0 = eg * 3;
  const float* xb = xyz + (size_t)b * N_PTS * 3;
  const float* xfb = x + (size_t)b * N_PTS * 128;
  const float* W0 = sW;
  const float* W1 = sW + 4096;

  float4 st[4];
  float acc[3][4];

  // ---- prologue: chunk0 loads in flight under gather/pe work ----
  LOADC(d1w, 0, 1024);                         // chunk 0 (d1w rows 0..31)
  if (t < KNN_K) sIdx[t] = knn[(size_t)q * KNN_K + t] & (N_PTS - 1);
  if (t >= 128) sXQ[t - 128] = xfb[(size_t)n * 128 + (t - 128)];
  __syncthreads();
  if (t < 72) {
    int e = t / 3, c = t - e * 3;
    sG[e * 4 + c] = xb[n * 3 + c] - xb[sIdx[e] * 3 + c];
  }
  #pragma unroll
  for (int ii = 0; ii < 3; ++ii) {             // gather v: 768 float4 loads
    int i4 = t + ii * 256;
    int e = i4 >> 5, c4 = (i4 & 31) * 4;
    *(float4*)&sA[e * 128 + c4] = *(const float4*)&xfb[(size_t)sIdx[e] * 128 + c4];
  }
  WRITEC(0, 1024);                             // chunk0 -> buf0
  LOADC(d1w, 4096, 896);                       // chunk 1 (d1w rows 32..59)
  __syncthreads();                             // sG visible
  for (int i = t; i < 24 * 60; i += 256) {     // positional encoding
    int e = i / 60, r = i - e * 60;
    int c = r / 20, inner = r - c * 20;
    int jj = (inner >= 10) ? inner - 10 : inner;
    float v = sG[e * 4 + c] * c_omega[jj];
    sPE[e * 64 + r] = (inner >= 10) ? __cosf(v) : __sinf(v);
  }
  __syncthreads();                             // sPE, sW[0] ready

  // ---- gemm1: h1 = relu(pe @ d1w + d1b) -> sB  (chunks 0,1) ----
  ZACC;
  WRITEC(1, 896);  LOADC(d2w, 0, 1024);        // c1->buf1, load c2
  cchunk<32>(sPE, 64, 0, W0, c0, e0, acc);
  __syncthreads();
  WRITEC(0, 1024); LOADC(d2w, 4096, 1024);     // c2->buf0, load c3
  cchunk<28>(sPE, 64, 32, W1, c0, e0, acc);
  epi(acc, d1b, sB, c0, e0, true);
  __syncthreads();

  // ---- gemm2: pos_enc = h1 @ d2w + d2b -> sC  (chunks 2..5) ----
  ZACC;
  WRITEC(1, 1024); LOADC(d2w, 8192, 1024);
  cchunk<32>(sB, 128, 0, W0, c0, e0, acc);
  __syncthreads();
  WRITEC(0, 1024); LOADC(d2w, 12288, 1024);
  cchunk<32>(sB, 128, 32, W1, c0, e0, acc);
  __syncthreads();
  WRITEC(1, 1024); LOADC(g1w, 0, 1024);
  cchunk<32>(sB, 128, 64, W0, c0, e0, acc);
  __syncthreads();
  WRITEC(0, 1024); LOADC(g1w, 4096, 1024);
  cchunk<32>(sB, 128, 96, W1, c0, e0, acc);
  epi(acc, d2b, sC, c0, e0, false);
  __syncthreads();

  // ---- elementwise: sB = xq - v + pe ; sA = v + pe ----
  #pragma unroll
  for (int ii = 0; ii < 12; ++ii) {
    int i = t + ii * 256;
    float v = sA[i], pe = sC[i];
    sB[i] = sXQ[i & 127] - v + pe;
    sA[i] = v + pe;
  }
  __syncthreads();

  // ---- gemm3: h2 = relu(u @ g1w + g1b) -> sC  (chunks 6..9) ----
  ZACC;
  WRITEC(1, 1024); LOADC(g1w, 8192, 1024);
  cchunk<32>(sB, 128, 0, W0, c0, e0, acc);
  __syncthreads();
  WRITEC(0, 1024); LOADC(g1w, 12288, 1024);
  cchunk<32>(sB, 128, 32, W1, c0, e0, acc);
  __syncthreads();
  WRITEC(1, 1024); LOADC(g2w, 0, 1024);
  cchunk<32>(sB, 128, 64, W0, c0, e0, acc);
  __syncthreads();
  WRITEC(0, 1024); LOADC(g2w, 4096, 1024);
  cchunk<32>(sB, 128, 96, W1, c0, e0, acc);
  epi(acc, g1b, sC, c0, e0, true);
  __syncthreads();

  // ---- gemm4: logits = h2 @ g2w + g2b -> sB  (chunks 10..13) ----
  ZACC;
  WRITEC(1, 1024); LOADC(g2w, 8192, 1024);
  cchunk<32>(sC, 128, 0, W0, c0, e0, acc);
  __syncthreads();
  WRITEC(0, 1024); LOADC(g2w, 12288, 1024);
  cchunk<32>(sC, 128, 32, W1, c0, e0, acc);
  __syncthreads();
  WRITEC(1, 1024); LOADC(fc2w, 0, 1024);
  cchunk<32>(sC, 128, 64, W0, c0, e0, acc);
  __syncthreads();
  WRITEC(0, 1024); LOADC(fc2w, 4096, 1024);
  cchunk<32>(sC, 128, 96, W1, c0, e0, acc);
  epi(acc, g2b, sB, c0, e0, false);
  __syncthreads();

  // ---- softmax over K per column + res accumulation ----
  if (t < 128) {
    const float scale = 0.08838834764831845f;  // 1/sqrt(128)
    float mx = -3.0e38f;
    #pragma unroll
    for (int e = 0; e < KNN_K; ++e) mx = fmaxf(mx, sB[e * 128 + t] * scale);
    float s = 0.f;
    #pragma unroll
    for (int e = 0; e < KNN_K; ++e) {
      float ex = __expf(sB[e * 128 + t] * scale - mx);
      sB[e * 128 + t] = ex;
      s += ex;
    }
    float inv = 1.0f / s;
    float r = 0.f;
    size_t base = (size_t)q * KNN_K * 128 + t;
    #pragma unroll
    for (int e = 0; e < KNN_K; ++e) {
      float p = sB[e * 128 + t] * inv;
      out_attn[base + (size_t)e * 128] = p;
      r = fmaf(p, sA[e * 128 + t], r);
    }
    sR[t] = r;
  }
  __syncthreads();

  // ---- fc2: out_res = sR @ fc2w + fc2b + xq  (chunks 14..17) ----
  float accf = 0.f;
  WRITEC(1, 1024); LOADC(fc2w, 8192, 1024);    // c15->buf1, load c16
  if (t < 128) {
    #pragma unroll 8
    for (int j = 0; j < 32; ++j) accf = fmaf(sR[j], W0[j * 128 + t], accf);
  }
  __syncthreads();
  WRITEC(0, 1024); LOADC(fc2w, 12288, 1024);   // c16->buf0, load c17
  if (t < 128) {
    #pragma unroll 8
    for (int j = 0; j < 32; ++j) accf = fmaf(sR[32 + j], W1[j * 128 + t], accf);
  }
  __syncthreads();
  WRITEC(1, 1024);                             // c17->buf1
  if (t < 128) {
    #pragma unroll 8
    for (int j = 0; j < 32; ++j) accf = fmaf(sR[64 + j], W0[j * 128 + t], accf);
  }
  __syncthreads();
  if (t < 128) {
    #pragma unroll 8
    for (int j = 0; j < 32; ++j) accf = fmaf(sR[96 + j], W1[j * 128 + t], accf);
    out_res[(size_t)q * 128 + t] = accf + fc2b[t] + sXQ[t];
  }
}

extern "C" void kernel_launch(void* const* d_in, const int* in_sizes, int n_in,
                              void* d_out, int out_size, void* d_ws, size_t ws_size,
                              hipStream_t stream) {
  const float* feat = (const float*)d_in[0];
  const float* xyz  = (const float*)d_in[1];
  const float* fc1w = (const float*)d_in[2];
  const float* fc1b = (const float*)d_in[3];
  const float* fc2w = (const float*)d_in[4];
  const float* fc2b = (const float*)d_in[5];
  const float* d1w  = (const float*)d_in[6];
  const float* d1b  = (const float*)d_in[7];
  const float* d2w  = (const float*)d_in[8];
  const float* d2b  = (const float*)d_in[9];
  const float* g1w  = (const float*)d_in[10];
  const float* g1b  = (const float*)d_in[11];
  const float* g2w  = (const float*)d_in[12];
  const float* g2b  = (const float*)d_in[13];

  float* x = (float*)d_ws;                                        // 2*8192*128 fp32 = 8 MB
  int* knn = (int*)((char*)d_ws + (size_t)2 * 8192 * 128 * 4);    // 2*8192*24 int32

  float* out_res  = (float*)d_out;                                // [2,8192,128] fp32
  float* out_attn = out_res + (size_t)2 * 8192 * 128;             // [2,8192,24,128] fp32

  fc1_kernel<<<dim3((2 * 8192 * 128) / 256), 256, 0, stream>>>(feat, fc1w, fc1b, x);
  knn_kernel<<<dim3(2 * 8192), 256, 0, stream>>>(xyz, knn);
  edge_kernel<<<dim3(2 * 8192), 256, 0, stream>>>(xyz, x, knn,
                                                  d1w, d1b, d2w, d2b,
                                                  g1w, g1b, g2w, g2b,
                                                  fc2w, fc2b, out_res, out_attn);
}

// Round 4
// 2085.129 us; speedup vs baseline: 1.9212x; 1.0036x over previous
//
#include <hip/hip_runtime.h>

#define N_PTS 8192
#define KNN_K 24

__constant__ float c_omega[10] = {
  1.0f, 0.3981071705534972f, 0.15848931924611134f, 0.06309573444801933f,
  0.025118864315095794f, 0.01f, 0.003981071705534973f, 0.0015848931924611134f,
  0.0006309573444801933f, 0.00025118864315095795f
};

__device__ __forceinline__ unsigned keyOf(float f) {
  unsigned u = __float_as_uint(f);
  return (u & 0x80000000u) ? ~u : (u | 0x80000000u);
}

// ---------------- fc1: x = features @ fc1_w + fc1_b ----------------
__global__ __launch_bounds__(256) void fc1_kernel(
    const float* __restrict__ feat, const float* __restrict__ w,
    const float* __restrict__ bias, float* __restrict__ x) {
  int gid = blockIdx.x * 256 + threadIdx.x;   // B*N*128 total
  int row = gid >> 7, c = gid & 127;
  const float* f = feat + (size_t)row * 32;
  float acc = bias[c];
  #pragma unroll
  for (int j = 0; j < 32; ++j) acc = fmaf(f[j], w[j * 128 + c], acc);
  x[gid] = acc;
}

// ---------------- KNN: exact top-24 by (fp32 dist, idx), keys in registers ------
__global__ __launch_bounds__(256) void knn_kernel(
    const float* __restrict__ xyz, int* __restrict__ knn) {
  __shared__ unsigned s_hist[256];
  __shared__ unsigned s_wsum[4];
  __shared__ unsigned long long s_surv[64];
  __shared__ unsigned s_pref, s_rem, s_cnt;

  const int q = blockIdx.x;
  const int b = q >> 13, n = q & (N_PTS - 1);
  const int t = threadIdx.x;
  const int lane = t & 63, wid = t >> 6;
  const float* xb = xyz + (size_t)b * N_PTS * 3;

  float qx = xb[n*3+0], qy = xb[n*3+1], qz = xb[n*3+2];
  // strict fp32 round-to-nearest, no fma — matches numpy association
  float sqq = __fadd_rn(__fadd_rn(__fmul_rn(qx,qx), __fmul_rn(qy,qy)), __fmul_rn(qz,qz));

  if (t == 0) { s_pref = 0u; s_rem = (unsigned)KNN_K; s_cnt = 0u; }

  unsigned key[32];
  #pragma unroll
  for (int j = 0; j < 32; ++j) {
    int m = t + 256 * j;
    float cx = xb[m*3+0], cy = xb[m*3+1], cz = xb[m*3+2];
    float sqc = __fadd_rn(__fadd_rn(__fmul_rn(cx,cx), __fmul_rn(cy,cy)), __fmul_rn(cz,cz));
    float dt  = __fadd_rn(__fadd_rn(__fmul_rn(qx,cx), __fmul_rn(qy,cy)), __fmul_rn(qz,cz));
    float d = __fsub_rn(__fadd_rn(sqq, sqc), __fmul_rn(2.0f, dt));
    key[j] = keyOf(d);
  }
  __syncthreads();   // covers s_pref/s_rem/s_cnt init

  // 4 radix passes, MSB->LSB: find exact key of 24th smallest (with duplicates)
  for (int p = 3; p >= 0; --p) {
    unsigned pref = s_pref;
    unsigned rem = s_rem;
    __syncthreads();
    s_hist[t] = 0u;
    __syncthreads();
    const int shift = 8 * p;
    for (int j = 0; j < 32; ++j) {
      unsigned k = key[j];
      bool match = (p == 3) || ((k >> (8 * (p + 1))) == (pref >> (8 * (p + 1))));
      unsigned bin = (k >> shift) & 255u;
      unsigned long long alive = __ballot(match);
      while (alive) {
        int leader = __ffsll(alive) - 1;
        unsigned lb = __shfl(bin, leader, 64);
        unsigned long long grp = __ballot(match && (bin == lb));
        if (lane == leader) atomicAdd(&s_hist[lb], (unsigned)__popcll(grp));
        alive &= ~grp;
      }
    }
    __syncthreads();
    unsigned v = s_hist[t];
    unsigned sum = v;
    #pragma unroll
    for (int off = 1; off < 64; off <<= 1) {
      unsigned up = __shfl_up(sum, off, 64);
      if (lane >= off) sum += up;
    }
    if (lane == 63) s_wsum[wid] = sum;
    __syncthreads();
    unsigned add = 0u;
    #pragma unroll
    for (int w2 = 0; w2 < 3; ++w2) if (w2 < wid) add += s_wsum[w2];
    unsigned cum = sum + add;
    unsigned prev = cum - v;
    if (cum >= rem && prev < rem) {
      s_pref = pref | (((unsigned)t) << shift);
      s_rem = rem - prev;
    }
    __syncthreads();
  }
  unsigned k24 = s_pref;

  #pragma unroll
  for (int j = 0; j < 32; ++j) {
    if (key[j] <= k24) {
      unsigned pp = atomicAdd(&s_cnt, 1u);
      if (pp < 64u)
        s_surv[pp] = (((unsigned long long)key[j]) << 32) | (unsigned)(t + 256 * j);
    }
  }
  __syncthreads();

  if (t < 64) {
    unsigned cnt = s_cnt;
    int S = (int)((cnt < 64u) ? cnt : 64u);
    unsigned long long kv = ~0ULL;
    if (t < S) kv = s_surv[t];
    for (int size = 2; size <= 64; size <<= 1) {
      for (int stride = size >> 1; stride > 0; stride >>= 1) {
        unsigned long long pk = __shfl_xor(kv, stride, 64);
        bool lower = (t & stride) == 0;
        bool up = (t & size) == 0;
        bool pLess = pk < kv;
        bool take = (lower == up) ? pLess : !pLess;
        kv = take ? pk : kv;
      }
    }
    if (t < KNN_K) knn[(size_t)q * KNN_K + t] = (int)(kv & 0xFFFFFFFFu);
  }
}

// ---------------- fused per-query edge pipeline ----------------
// LDS-pipe-optimized: activations read as float4 over K (28 b128/chunk/thread
// instead of 96 b32 + 32 b128), 16-row double-buffered weight chunks staged
// through registers (loads issued one chunk ahead), LDS total 54.2 KB ->
// 3 blocks/CU (12 waves) for ds_read latency hiding.

#define ZACC { _Pragma("unroll") for (int zr = 0; zr < 3; ++zr) \
  { acc[zr][0] = 0.f; acc[zr][1] = 0.f; acc[zr][2] = 0.f; acc[zr][3] = 0.f; } }

__device__ __forceinline__ void loadc(const float* __restrict__ W, int foff, int cnt4,
                                      int t, float4 (&st)[2]) {
  #pragma unroll
  for (int rr = 0; rr < 2; ++rr) {
    int i4 = t + rr * 256;
    if (i4 < cnt4) st[rr] = *(const float4*)&W[foff + i4 * 4];
  }
}

__device__ __forceinline__ void writec(float* __restrict__ buf, int cnt4,
                                       int t, const float4 (&st)[2]) {
  #pragma unroll
  for (int rr = 0; rr < 2; ++rr) {
    int i4 = t + rr * 256;
    if (i4 < cnt4) *(float4*)&buf[i4 * 4] = st[rr];
  }
}

template<int ROWS>
__device__ __forceinline__ void cchunk(const float* __restrict__ inL, int ldin, int kbase,
                                       const float* __restrict__ Wb,
                                       int c0, int e0, float (&acc)[3][4]) {
  #pragma unroll
  for (int j = 0; j < ROWS; j += 4) {
    float4 p0 = *(const float4*)&inL[(e0 + 0) * ldin + kbase + j];
    float4 p1 = *(const float4*)&inL[(e0 + 1) * ldin + kbase + j];
    float4 p2 = *(const float4*)&inL[(e0 + 2) * ldin + kbase + j];
    float pa[3][4] = {{p0.x, p0.y, p0.z, p0.w},
                      {p1.x, p1.y, p1.z, p1.w},
                      {p2.x, p2.y, p2.z, p2.w}};
    #pragma unroll
    for (int jj = 0; jj < 4; ++jj) {
      float4 w = *(const float4*)&Wb[(j + jj) * 128 + c0];
      #pragma unroll
      for (int r = 0; r < 3; ++r) {
        acc[r][0] = fmaf(pa[r][jj], w.x, acc[r][0]);
        acc[r][1] = fmaf(pa[r][jj], w.y, acc[r][1]);
        acc[r][2] = fmaf(pa[r][jj], w.z, acc[r][2]);
        acc[r][3] = fmaf(pa[r][jj], w.w, acc[r][3]);
      }
    }
  }
}

__device__ __forceinline__ void epi(float (&acc)[3][4], const float* __restrict__ bg,
                                    float* __restrict__ out, int c0, int e0, bool relu) {
  float4 bb = *(const float4*)&bg[c0];
  #pragma unroll
  for (int r = 0; r < 3; ++r) {
    float4 o;
    o.x = acc[r][0] + bb.x; o.y = acc[r][1] + bb.y;
    o.z = acc[r][2] + bb.z; o.w = acc[r][3] + bb.w;
    if (relu) { o.x = fmaxf(o.x, 0.f); o.y = fmaxf(o.y, 0.f);
                o.z = fmaxf(o.z, 0.f); o.w = fmaxf(o.w, 0.f); }
    *(float4*)&out[(e0 + r) * 128 + c0] = o;
  }
}

// 8x16-row chunk gemm: computes 24x128 = inL @ W (+bias, relu) with staged
// double-buffered weights. Entry invariant: buf0 = this gemm's chunk0,
// st = chunk1. Exit: buf0 = next W's chunk0, st = next W's chunk1.
#define GEMM8(INL, LDIN, WTHIS, WNEXT, BIAS, OUT, RELU) \
  ZACC; \
  _Pragma("unroll 1") \
  for (int k = 0; k < 8; ++k) { \
    int pb = k & 1; \
    writec(sW + (pb ^ 1) * 2048, 512, t, st); \
    int nk = k + 2; \
    const float* lw = (nk < 8) ? (WTHIS) : (WNEXT); \
    int lo = ((nk < 8) ? nk : nk - 8) * 2048; \
    loadc(lw, lo, 512, t, st); \
    cchunk<16>(INL, LDIN, k * 16, sW + pb * 2048, c0, e0, acc); \
    __syncthreads(); \
  } \
  epi(acc, BIAS, OUT, c0, e0, RELU); \
  __syncthreads();

__global__ __launch_bounds__(256, 3) void edge_kernel(
    const float* __restrict__ xyz, const float* __restrict__ x,
    const int* __restrict__ knn,
    const float* __restrict__ d1w, const float* __restrict__ d1b,
    const float* __restrict__ d2w, const float* __restrict__ d2b,
    const float* __restrict__ g1w, const float* __restrict__ g1b,
    const float* __restrict__ g2w, const float* __restrict__ g2b,
    const float* __restrict__ fc2w, const float* __restrict__ fc2b,
    float* __restrict__ out_res, float* __restrict__ out_attn) {
  __shared__ __align__(16) float sW[4096];   // 16 KB: two 8 KB 16-row weight buffers
  __shared__ __align__(16) float sA[3072];   // v -> v+pos_enc
  __shared__ __align__(16) float sB[3072];   // h1 -> u -> logits/probs
  __shared__ __align__(16) float sC[3072];   // pe(ld64) -> pos_enc -> h2 -> sR
  __shared__ __align__(16) float sXQ[128];
  __shared__ float sG[96];
  __shared__ int sIdx[KNN_K];
  // total LDS = 16384 + 36864 + 512 + 384 + 96 = 54240 B  ->  3 blocks/CU

  const int q = blockIdx.x;
  const int b = q >> 13, n = q & (N_PTS - 1);
  const int t = threadIdx.x;
  const int cg = t & 31, eg = t >> 5;
  const int c0 = cg * 4, e0 = eg * 3;
  const float* xb = xyz + (size_t)b * N_PTS * 3;
  const float* xfb = x + (size_t)b * N_PTS * 128;

  float4 st[2];
  float acc[3][4];

  // ---- prologue ----
  loadc(d1w, 0, 512, t, st);                 // c0 (d1w rows 0..15)
  if (t < KNN_K) sIdx[t] = knn[(size_t)q * KNN_K + t] & (N_PTS - 1);
  if (t >= 128) sXQ[t - 128] = xfb[(size_t)n * 128 + (t - 128)];
  __syncthreads();                           // sIdx/sXQ ready
  writec(sW, 512, t, st);                    // c0 -> buf0
  loadc(d1w, 2048, 512, t, st);              // c1 in flight under gather/sG
  if (t < 72) {
    int e = t / 3, c = t - e * 3;
    sG[e * 4 + c] = xb[n * 3 + c] - xb[sIdx[e] * 3 + c];
  }
  #pragma unroll
  for (int ii = 0; ii < 3; ++ii) {           // gather v -> sA (768 float4)
    int i4 = t + ii * 256;
    int e = i4 >> 5, c4 = (i4 & 31) * 4;
    *(float4*)&sA[e * 128 + c4] = *(const float4*)&xfb[(size_t)sIdx[e] * 128 + c4];
  }
  __syncthreads();                           // sG visible
  for (int i = t; i < 24 * 60; i += 256) {   // positional encoding -> sC (ld 64)
    int e = i / 60, r = i - e * 60;
    int c = r / 20, inner = r - c * 20;
    int jj = (inner >= 10) ? inner - 10 : inner;
    float v = sG[e * 4 + c] * c_omega[jj];
    sC[e * 64 + r] = (inner >= 10) ? __cosf(v) : __sinf(v);
  }
  __syncthreads();                           // sC(pe), buf0 ready

  // ---- gemm1: h1 = relu(pe @ d1w + d1b) -> sB  (chunks 16,16,16,12) ----
  ZACC;
  writec(sW + 2048, 512, t, st); loadc(d1w, 4096, 512, t, st);   // c1->buf1, load c2
  cchunk<16>(sC, 64, 0, sW, c0, e0, acc);
  __syncthreads();
  writec(sW, 512, t, st); loadc(d1w, 6144, 384, t, st);          // c2->buf0, load c3
  cchunk<16>(sC, 64, 16, sW + 2048, c0, e0, acc);
  __syncthreads();
  writec(sW + 2048, 384, t, st); loadc(d2w, 0, 512, t, st);      // c3->buf1, load d2w c0
  cchunk<16>(sC, 64, 32, sW, c0, e0, acc);
  __syncthreads();
  writec(sW, 512, t, st); loadc(d2w, 2048, 512, t, st);          // d2w c0->buf0, load c1
  cchunk<12>(sC, 64, 48, sW + 2048, c0, e0, acc);
  epi(acc, d1b, sB, c0, e0, true);
  __syncthreads();

  // ---- gemm2: pos_enc = h1 @ d2w + d2b -> sC ----
  GEMM8(sB, 128, d2w, g1w, d2b, sC, false);

  // ---- elementwise: sB = xq - v + pe ; sA = v + pe ----
  #pragma unroll
  for (int ii = 0; ii < 12; ++ii) {
    int i = t + ii * 256;
    float v = sA[i], pe = sC[i];
    sB[i] = sXQ[i & 127] - v + pe;
    sA[i] = v + pe;
  }
  __syncthreads();

  // ---- gemm3: h2 = relu(u @ g1w + g1b) -> sC ----
  GEMM8(sB, 128, g1w, g2w, g1b, sC, true);

  // ---- gemm4: logits = h2 @ g2w + g2b -> sB ----
  GEMM8(sC, 128, g2w, fc2w, g2b, sB, false);

  // ---- softmax over K per column + res accumulation (sR = sC[0..127]) ----
  if (t < 128) {
    const float scale = 0.08838834764831845f;  // 1/sqrt(128)
    float mx = -3.0e38f;
    #pragma unroll
    for (int e = 0; e < KNN_K; ++e) mx = fmaxf(mx, sB[e * 128 + t] * scale);
    float s = 0.f;
    #pragma unroll
    for (int e = 0; e < KNN_K; ++e) {
      float ex = __expf(sB[e * 128 + t] * scale - mx);
      sB[e * 128 + t] = ex;
      s += ex;
    }
    float inv = 1.0f / s;
    float r = 0.f;
    size_t base = (size_t)q * KNN_K * 128 + t;
    #pragma unroll
    for (int e = 0; e < KNN_K; ++e) {
      float p = sB[e * 128 + t] * inv;
      out_attn[base + (size_t)e * 128] = p;
      r = fmaf(p, sA[e * 128 + t], r);
    }
    sC[t] = r;
  }
  __syncthreads();

  // ---- fc2: out_res = sR @ fc2w + fc2b + xq  (8 chunks; entry buf0=c0, st=c1) ----
  float accf = 0.f;
  #pragma unroll 1
  for (int k = 0; k < 8; ++k) {
    int pb = k & 1;
    if (k < 7) writec(sW + (pb ^ 1) * 2048, 512, t, st);
    if (k < 6) loadc(fc2w, (k + 2) * 2048, 512, t, st);
    if (t < 128) {
      const float* Wb = sW + pb * 2048;
      #pragma unroll
      for (int j = 0; j < 16; ++j)
        accf = fmaf(sC[k * 16 + j], Wb[j * 128 + t], accf);
    }
    __syncthreads();
  }
  if (t < 128)
    out_res[(size_t)q * 128 + t] = accf + fc2b[t] + sXQ[t];
}

extern "C" void kernel_launch(void* const* d_in, const int* in_sizes, int n_in,
                              void* d_out, int out_size, void* d_ws, size_t ws_size,
                              hipStream_t stream) {
  const float* feat = (const float*)d_in[0];
  const float* xyz  = (const float*)d_in[1];
  const float* fc1w = (const float*)d_in[2];
  const float* fc1b = (const float*)d_in[3];
  const float* fc2w = (const float*)d_in[4];
  const float* fc2b = (const float*)d_in[5];
  const float* d1w  = (const float*)d_in[6];
  const float* d1b  = (const float*)d_in[7];
  const float* d2w  = (const float*)d_in[8];
  const float* d2b  = (const float*)d_in[9];
  const float* g1w  = (const float*)d_in[10];
  const float* g1b  = (const float*)d_in[11];
  const float* g2w  = (const float*)d_in[12];
  const float* g2b  = (const float*)d_in[13];

  float* x = (float*)d_ws;                                        // 2*8192*128 fp32 = 8 MB
  int* knn = (int*)((char*)d_ws + (size_t)2 * 8192 * 128 * 4);    // 2*8192*24 int32

  float* out_res  = (float*)d_out;                                // [2,8192,128] fp32
  float* out_attn = out_res + (size_t)2 * 8192 * 128;             // [2,8192,24,128] fp32

  fc1_kernel<<<dim3((2 * 8192 * 128) / 256), 256, 0, stream>>>(feat, fc1w, fc1b, x);
  knn_kernel<<<dim3(2 * 8192), 256, 0, stream>>>(xyz, knn);
  edge_kernel<<<dim3(2 * 8192), 256, 0, stream>>>(xyz, x, knn,
                                                  d1w, d1b, d2w, d2b,
                                                  g1w, g1b, g2w, g2b,
                                                  fc2w, fc2b, out_res, out_attn);
}

// Round 5
// 1082.385 us; speedup vs baseline: 3.7011x; 1.9264x over previous
//
#include <hip/hip_runtime.h>

#define N_PTS 8192
#define KNN_K 24

typedef __attribute__((ext_vector_type(8))) short short8;
typedef __attribute__((ext_vector_type(4))) short short4v;
typedef __attribute__((ext_vector_type(4))) float f32x4;

__constant__ float c_omega[10] = {
  1.0f, 0.3981071705534972f, 0.15848931924611134f, 0.06309573444801933f,
  0.025118864315095794f, 0.01f, 0.003981071705534973f, 0.0015848931924611134f,
  0.0006309573444801933f, 0.00025118864315095795f
};

__device__ __forceinline__ unsigned keyOf(float f) {
  unsigned u = __float_as_uint(f);
  return (u & 0x80000000u) ? ~u : (u | 0x80000000u);
}

// split fp32 -> bf16 hi + bf16 lo (x ~= hi + lo, lo exact residual then RN)
__device__ __forceinline__ void splitbf(float x, unsigned short &h, unsigned short &l) {
  unsigned u = __float_as_uint(x);
  unsigned hb = (u + 0x7FFFu + ((u >> 16) & 1u)) & 0xFFFF0000u;
  h = (unsigned short)(hb >> 16);
  float lf = x - __uint_as_float(hb);
  unsigned ul = __float_as_uint(lf);
  l = (unsigned short)((ul + 0x7FFFu + ((ul >> 16) & 1u)) >> 16);
}

// ---------------- fc1: x = features @ fc1_w + fc1_b ----------------
__global__ __launch_bounds__(256) void fc1_kernel(
    const float* __restrict__ feat, const float* __restrict__ w,
    const float* __restrict__ bias, float* __restrict__ x) {
  int gid = blockIdx.x * 256 + threadIdx.x;   // B*N*128 total
  int row = gid >> 7, c = gid & 127;
  const float* f = feat + (size_t)row * 32;
  float acc = bias[c];
  #pragma unroll
  for (int j = 0; j < 32; ++j) acc = fmaf(f[j], w[j * 128 + c], acc);
  x[gid] = acc;
}

// ---------------- KNN: exact top-24 by (fp32 dist, idx), keys in registers ------
__global__ __launch_bounds__(256) void knn_kernel(
    const float* __restrict__ xyz, int* __restrict__ knn) {
  __shared__ unsigned s_hist[256];
  __shared__ unsigned s_wsum[4];
  __shared__ unsigned long long s_surv[64];
  __shared__ unsigned s_pref, s_rem, s_cnt;

  const int q = blockIdx.x;
  const int b = q >> 13, n = q & (N_PTS - 1);
  const int t = threadIdx.x;
  const int lane = t & 63, wid = t >> 6;
  const float* xb = xyz + (size_t)b * N_PTS * 3;

  float qx = xb[n*3+0], qy = xb[n*3+1], qz = xb[n*3+2];
  // strict fp32 round-to-nearest, no fma — matches numpy association
  float sqq = __fadd_rn(__fadd_rn(__fmul_rn(qx,qx), __fmul_rn(qy,qy)), __fmul_rn(qz,qz));

  if (t == 0) { s_pref = 0u; s_rem = (unsigned)KNN_K; s_cnt = 0u; }

  unsigned key[32];
  #pragma unroll
  for (int j = 0; j < 32; ++j) {
    int m = t + 256 * j;
    float cx = xb[m*3+0], cy = xb[m*3+1], cz = xb[m*3+2];
    float sqc = __fadd_rn(__fadd_rn(__fmul_rn(cx,cx), __fmul_rn(cy,cy)), __fmul_rn(cz,cz));
    float dt  = __fadd_rn(__fadd_rn(__fmul_rn(qx,cx), __fmul_rn(qy,cy)), __fmul_rn(qz,cz));
    float d = __fsub_rn(__fadd_rn(sqq, sqc), __fmul_rn(2.0f, dt));
    key[j] = keyOf(d);
  }
  __syncthreads();   // covers s_pref/s_rem/s_cnt init

  for (int p = 3; p >= 0; --p) {
    unsigned pref = s_pref;
    unsigned rem = s_rem;
    __syncthreads();
    s_hist[t] = 0u;
    __syncthreads();
    const int shift = 8 * p;
    for (int j = 0; j < 32; ++j) {
      unsigned k = key[j];
      bool match = (p == 3) || ((k >> (8 * (p + 1))) == (pref >> (8 * (p + 1))));
      unsigned bin = (k >> shift) & 255u;
      unsigned long long alive = __ballot(match);
      while (alive) {
        int leader = __ffsll(alive) - 1;
        unsigned lb = __shfl(bin, leader, 64);
        unsigned long long grp = __ballot(match && (bin == lb));
        if (lane == leader) atomicAdd(&s_hist[lb], (unsigned)__popcll(grp));
        alive &= ~grp;
      }
    }
    __syncthreads();
    unsigned v = s_hist[t];
    unsigned sum = v;
    #pragma unroll
    for (int off = 1; off < 64; off <<= 1) {
      unsigned up = __shfl_up(sum, off, 64);
      if (lane >= off) sum += up;
    }
    if (lane == 63) s_wsum[wid] = sum;
    __syncthreads();
    unsigned add = 0u;
    #pragma unroll
    for (int w2 = 0; w2 < 3; ++w2) if (w2 < wid) add += s_wsum[w2];
    unsigned cum = sum + add;
    unsigned prev = cum - v;
    if (cum >= rem && prev < rem) {
      s_pref = pref | (((unsigned)t) << shift);
      s_rem = rem - prev;
    }
    __syncthreads();
  }
  unsigned k24 = s_pref;

  #pragma unroll
  for (int j = 0; j < 32; ++j) {
    if (key[j] <= k24) {
      unsigned pp = atomicAdd(&s_cnt, 1u);
      if (pp < 64u)
        s_surv[pp] = (((unsigned long long)key[j]) << 32) | (unsigned)(t + 256 * j);
    }
  }
  __syncthreads();

  if (t < 64) {
    unsigned cnt = s_cnt;
    int S = (int)((cnt < 64u) ? cnt : 64u);
    unsigned long long kv = ~0ULL;
    if (t < S) kv = s_surv[t];
    for (int size = 2; size <= 64; size <<= 1) {
      for (int stride = size >> 1; stride > 0; stride >>= 1) {
        unsigned long long pk = __shfl_xor(kv, stride, 64);
        bool lower = (t & stride) == 0;
        bool up = (t & size) == 0;
        bool pLess = pk < kv;
        bool take = (lower == up) ? pLess : !pLess;
        kv = take ? pk : kv;
      }
    }
    if (t < KNN_K) knn[(size_t)q * KNN_K + t] = (int)(kv & 0xFFFFFFFFu);
  }
}

// ---------------- MFMA 24x128x128 gemm: D = U @ W, U bf16 hi/lo in LDS --------
// A-frag: lane&15 = row, k = kb*32 + (lane>>4)*8 + j (any consistent k-map works
// since A and B share it). B loaded fp32 straight from global (L2) per lane and
// split to bf16 in-register. C/D layout (m89-verified): col=lane&15,
// row=(lane>>4)*4+reg. 6 MFMA per (kb,nt): hh(x2 Mtiles), lh(x2), hl(x2).
__device__ __forceinline__ void mfma_gemm128(
    const unsigned short* sUh, const unsigned short* sUl,
    const float* __restrict__ W, int n0, int lane, f32x4 (&acc)[2][2]) {
  const int lo4 = lane & 15, hi4 = lane >> 4;
  #pragma unroll
  for (int mt = 0; mt < 2; ++mt)
    #pragma unroll
    for (int nt = 0; nt < 2; ++nt)
      acc[mt][nt] = (f32x4){0.f, 0.f, 0.f, 0.f};
  #pragma unroll
  for (int kb = 0; kb < 4; ++kb) {
    const int krow = kb * 32 + hi4 * 8;
    short8 ah0 = *(const short8*)&sUh[lo4 * 136 + krow];
    short8 ah1 = *(const short8*)&sUh[(16 + lo4) * 136 + krow];
    short8 al0 = *(const short8*)&sUl[lo4 * 136 + krow];
    short8 al1 = *(const short8*)&sUl[(16 + lo4) * 136 + krow];
    #pragma unroll
    for (int nt = 0; nt < 2; ++nt) {
      const float* wb = W + (size_t)krow * 128 + n0 + nt * 16 + lo4;
      short8 bh, bl;
      #pragma unroll
      for (int j = 0; j < 8; ++j) {
        unsigned short h, l;
        splitbf(wb[(size_t)j * 128], h, l);
        bh[j] = (short)h; bl[j] = (short)l;
      }
      acc[0][nt] = __builtin_amdgcn_mfma_f32_16x16x32_bf16(ah0, bh, acc[0][nt], 0, 0, 0);
      acc[1][nt] = __builtin_amdgcn_mfma_f32_16x16x32_bf16(ah1, bh, acc[1][nt], 0, 0, 0);
      acc[0][nt] = __builtin_amdgcn_mfma_f32_16x16x32_bf16(al0, bh, acc[0][nt], 0, 0, 0);
      acc[1][nt] = __builtin_amdgcn_mfma_f32_16x16x32_bf16(al1, bh, acc[1][nt], 0, 0, 0);
      acc[0][nt] = __builtin_amdgcn_mfma_f32_16x16x32_bf16(ah0, bl, acc[0][nt], 0, 0, 0);
      acc[1][nt] = __builtin_amdgcn_mfma_f32_16x16x32_bf16(ah1, bl, acc[1][nt], 0, 0, 0);
    }
  }
}

__global__ __launch_bounds__(256, 2) void edge_kernel(
    const float* __restrict__ xyz, const float* __restrict__ x,
    const int* __restrict__ knn,
    const float* __restrict__ d1w, const float* __restrict__ d1b,
    const float* __restrict__ d2w, const float* __restrict__ d2b,
    const float* __restrict__ g1w, const float* __restrict__ g1b,
    const float* __restrict__ g2w, const float* __restrict__ g2b,
    const float* __restrict__ fc2w, const float* __restrict__ fc2b,
    float* __restrict__ out_res, float* __restrict__ out_attn) {
  __shared__ __align__(16) float sW[4096];            // 16 KB weight staging (stage1, fc2)
  __shared__ __align__(16) float sA[3072];            // v -> v+pos_enc
  __shared__ __align__(16) float sB[3072];            // logits -> probs
  __shared__ __align__(16) float sC[3072];            // pe(ld64) -> pos_enc -> r(0:128)
  __shared__ __align__(16) unsigned short sUh[32 * 136];  // bf16-hi activations (pad rows 24-31)
  __shared__ __align__(16) unsigned short sUl[32 * 136];  // bf16-lo
  __shared__ __align__(16) float sXQ[128];
  __shared__ float sG[96];
  __shared__ int sIdx[KNN_K];
  // LDS total = 16384 + 3*12288 + 2*8704 + 512 + 384 + 96 = 71648 B -> 2 blocks/CU

  const int q = blockIdx.x;
  const int b = q >> 13, n = q & (N_PTS - 1);
  const int t = threadIdx.x;
  const int cg = t & 31, eg = t >> 5;
  const int c0 = cg * 4, e0 = eg * 3;                 // stage1 fp32 layout
  const int lane = t & 63, wid = t >> 6;
  const int lo4 = lane & 15, hi4 = lane >> 4;
  const int n0 = wid * 32;                            // MFMA: wave owns 32 cols
  const float* xb = xyz + (size_t)b * N_PTS * 3;
  const float* xfb = x + (size_t)b * N_PTS * 128;

  // ---- prologue ----
  if (t < KNN_K) sIdx[t] = knn[(size_t)q * KNN_K + t] & (N_PTS - 1);
  if (t >= 128) sXQ[t - 128] = xfb[(size_t)n * 128 + (t - 128)];
  __syncthreads();
  if (t < 72) {
    int e = t / 3, c = t - e * 3;
    sG[e * 4 + c] = xb[n * 3 + c] - xb[sIdx[e] * 3 + c];
  }
  #pragma unroll
  for (int ii = 0; ii < 3; ++ii) {                    // gather v -> sA (768 float4)
    int i4 = t + ii * 256;
    int e = i4 >> 5, c4 = (i4 & 31) * 4;
    *(float4*)&sA[e * 128 + c4] = *(const float4*)&xfb[(size_t)sIdx[e] * 128 + c4];
  }
  __syncthreads();                                    // sG visible
  for (int i = t; i < 24 * 60; i += 256) {            // positional encoding -> sC (ld 64)
    int e = i / 60, r = i - e * 60;
    int c = r / 20, inner = r - c * 20;
    int jj = (inner >= 10) ? inner - 10 : inner;
    float v = sG[e * 4 + c] * c_omega[jj];
    sC[e * 64 + r] = (inner >= 10) ? __cosf(v) : __sinf(v);
  }
  __syncthreads();

  // ---- stage1 (fp32 VALU): h1 = relu(pe @ d1w + d1b) -> split into sUh/sUl ----
  {
    float a1[3][4];
    #pragma unroll
    for (int r = 0; r < 3; ++r)
      { a1[r][0] = 0.f; a1[r][1] = 0.f; a1[r][2] = 0.f; a1[r][3] = 0.f; }
    #pragma unroll
    for (int h = 0; h < 2; ++h) {
      const int rows = h ? 28 : 32;
      for (int i = t * 4; i < rows * 128; i += 1024)
        *(float4*)&sW[i] = *(const float4*)&d1w[h * 4096 + i];
      __syncthreads();
      #pragma unroll 8
      for (int j = 0; j < rows; ++j) {
        float4 w = *(const float4*)&sW[j * 128 + c0];
        #pragma unroll
        for (int r = 0; r < 3; ++r) {
          float p = sC[(e0 + r) * 64 + h * 32 + j];
          a1[r][0] = fmaf(p, w.x, a1[r][0]);
          a1[r][1] = fmaf(p, w.y, a1[r][1]);
          a1[r][2] = fmaf(p, w.z, a1[r][2]);
          a1[r][3] = fmaf(p, w.w, a1[r][3]);
        }
      }
      __syncthreads();
    }
    float4 bb = *(const float4*)&d1b[c0];
    #pragma unroll
    for (int r = 0; r < 3; ++r) {
      float v0 = fmaxf(a1[r][0] + bb.x, 0.f);
      float v1 = fmaxf(a1[r][1] + bb.y, 0.f);
      float v2 = fmaxf(a1[r][2] + bb.z, 0.f);
      float v3 = fmaxf(a1[r][3] + bb.w, 0.f);
      unsigned short h0, l0, h1, l1, h2, l2, h3, l3;
      splitbf(v0, h0, l0); splitbf(v1, h1, l1);
      splitbf(v2, h2, l2); splitbf(v3, h3, l3);
      short4v hv = {(short)h0, (short)h1, (short)h2, (short)h3};
      short4v lv = {(short)l0, (short)l1, (short)l2, (short)l3};
      *(short4v*)&sUh[(e0 + r) * 136 + c0] = hv;
      *(short4v*)&sUl[(e0 + r) * 136 + c0] = lv;
    }
  }
  __syncthreads();                                    // sU(h1) ready

  // ---- gemm2 (MFMA): pos_enc = h1 @ d2w + d2b -> sC fp32 ----
  {
    f32x4 a2[2][2];
    mfma_gemm128(sUh, sUl, d2w, n0, lane, a2);
    float bb0 = d2b[n0 + lo4], bb1 = d2b[n0 + 16 + lo4];
    #pragma unroll
    for (int mt = 0; mt < 2; ++mt)
      #pragma unroll
      for (int nt = 0; nt < 2; ++nt)
        #pragma unroll
        for (int bx = 0; bx < 4; ++bx) {
          int row = mt * 16 + hi4 * 4 + bx;
          if (row < 24)
            sC[row * 128 + n0 + nt * 16 + lo4] = a2[mt][nt][bx] + (nt ? bb1 : bb0);
        }
  }
  __syncthreads();

  // ---- elementwise: u = xq - v + pe (split -> sU) ; sA = v + pe ----
  #pragma unroll
  for (int ii = 0; ii < 3; ++ii) {
    int i4 = t + ii * 256;
    int e = i4 >> 5, c4 = (i4 & 31) * 4;
    float4 v  = *(float4*)&sA[e * 128 + c4];
    float4 pe = *(float4*)&sC[e * 128 + c4];
    float4 xq = *(float4*)&sXQ[c4];
    float4 vp, u;
    u.x = xq.x - v.x + pe.x;  vp.x = v.x + pe.x;
    u.y = xq.y - v.y + pe.y;  vp.y = v.y + pe.y;
    u.z = xq.z - v.z + pe.z;  vp.z = v.z + pe.z;
    u.w = xq.w - v.w + pe.w;  vp.w = v.w + pe.w;
    *(float4*)&sA[e * 128 + c4] = vp;
    unsigned short h0, l0, h1, l1, h2, l2, h3, l3;
    splitbf(u.x, h0, l0); splitbf(u.y, h1, l1);
    splitbf(u.z, h2, l2); splitbf(u.w, h3, l3);
    short4v hv = {(short)h0, (short)h1, (short)h2, (short)h3};
    short4v lv = {(short)l0, (short)l1, (short)l2, (short)l3};
    *(short4v*)&sUh[e * 136 + c4] = hv;
    *(short4v*)&sUl[e * 136 + c4] = lv;
  }
  __syncthreads();

  // ---- gemm3 (MFMA): h2 = relu(u @ g1w + g1b) -> split back into sU ----
  {
    f32x4 a3[2][2];
    mfma_gemm128(sUh, sUl, g1w, n0, lane, a3);
    float bb0 = g1b[n0 + lo4], bb1 = g1b[n0 + 16 + lo4];
    __syncthreads();                                  // all u-reads done before overwrite
    #pragma unroll
    for (int mt = 0; mt < 2; ++mt)
      #pragma unroll
      for (int nt = 0; nt < 2; ++nt)
        #pragma unroll
        for (int bx = 0; bx < 4; ++bx) {
          int row = mt * 16 + hi4 * 4 + bx;
          if (row < 24) {
            float vv = fmaxf(a3[mt][nt][bx] + (nt ? bb1 : bb0), 0.f);
            unsigned short hh, ll;
            splitbf(vv, hh, ll);
            int col = n0 + nt * 16 + lo4;
            sUh[row * 136 + col] = hh;
            sUl[row * 136 + col] = ll;
          }
        }
  }
  __syncthreads();

  // ---- gemm4 (MFMA): logits = h2 @ g2w + g2b -> sB fp32 ----
  {
    f32x4 a4[2][2];
    mfma_gemm128(sUh, sUl, g2w, n0, lane, a4);
    float bb0 = g2b[n0 + lo4], bb1 = g2b[n0 + 16 + lo4];
    #pragma unroll
    for (int mt = 0; mt < 2; ++mt)
      #pragma unroll
      for (int nt = 0; nt < 2; ++nt)
        #pragma unroll
        for (int bx = 0; bx < 4; ++bx) {
          int row = mt * 16 + hi4 * 4 + bx;
          if (row < 24)
            sB[row * 128 + n0 + nt * 16 + lo4] = a4[mt][nt][bx] + (nt ? bb1 : bb0);
        }
  }
  __syncthreads();

  // ---- softmax over K per column + res accumulation (r -> sC[0:128]) ----
  if (t < 128) {
    const float scale = 0.08838834764831845f;  // 1/sqrt(128)
    float mx = -3.0e38f;
    #pragma unroll
    for (int e = 0; e < KNN_K; ++e) mx = fmaxf(mx, sB[e * 128 + t] * scale);
    float s = 0.f;
    #pragma unroll
    for (int e = 0; e < KNN_K; ++e) {
      float ex = __expf(sB[e * 128 + t] * scale - mx);
      sB[e * 128 + t] = ex;
      s += ex;
    }
    float inv = 1.0f / s;
    float r = 0.f;
    size_t base = (size_t)q * KNN_K * 128 + t;
    #pragma unroll
    for (int e = 0; e < KNN_K; ++e) {
      float p = sB[e * 128 + t] * inv;
      out_attn[base + (size_t)e * 128] = p;
      r = fmaf(p, sA[e * 128 + t], r);
    }
    sC[t] = r;
  }
  __syncthreads();

  // ---- fc2: out_res = r @ fc2w + fc2b + xq ----
  float accf = 0.f;
  #pragma unroll
  for (int h = 0; h < 4; ++h) {
    for (int i = t * 4; i < 4096; i += 1024)
      *(float4*)&sW[i] = *(const float4*)&fc2w[h * 4096 + i];
    __syncthreads();
    if (t < 128) {
      #pragma unroll 8
      for (int j = 0; j < 32; ++j)
        accf = fmaf(sC[h * 32 + j], sW[j * 128 + t], accf);
    }
    __syncthreads();
  }
  if (t < 128)
    out_res[(size_t)q * 128 + t] = accf + fc2b[t] + sXQ[t];
}

extern "C" void kernel_launch(void* const* d_in, const int* in_sizes, int n_in,
                              void* d_out, int out_size, void* d_ws, size_t ws_size,
                              hipStream_t stream) {
  const float* feat = (const float*)d_in[0];
  const float* xyz  = (const float*)d_in[1];
  const float* fc1w = (const float*)d_in[2];
  const float* fc1b = (const float*)d_in[3];
  const float* fc2w = (const float*)d_in[4];
  const float* fc2b = (const float*)d_in[5];
  const float* d1w  = (const float*)d_in[6];
  const float* d1b  = (const float*)d_in[7];
  const float* d2w  = (const float*)d_in[8];
  const float* d2b  = (const float*)d_in[9];
  const float* g1w  = (const float*)d_in[10];
  const float* g1b  = (const float*)d_in[11];
  const float* g2w  = (const float*)d_in[12];
  const float* g2b  = (const float*)d_in[13];

  float* x = (float*)d_ws;                                        // 2*8192*128 fp32 = 8 MB
  int* knn = (int*)((char*)d_ws + (size_t)2 * 8192 * 128 * 4);    // 2*8192*24 int32

  float* out_res  = (float*)d_out;                                // [2,8192,128] fp32
  float* out_attn = out_res + (size_t)2 * 8192 * 128;             // [2,8192,24,128] fp32

  fc1_kernel<<<dim3((2 * 8192 * 128) / 256), 256, 0, stream>>>(feat, fc1w, fc1b, x);
  knn_kernel<<<dim3(2 * 8192), 256, 0, stream>>>(xyz, knn);
  edge_kernel<<<dim3(2 * 8192), 256, 0, stream>>>(xyz, x, knn,
                                                  d1w, d1b, d2w, d2b,
                                                  g1w, g1b, g2w, g2b,
                                                  fc2w, fc2b, out_res, out_attn);
}